// Round 6
// baseline (1147.751 us; speedup 1.0000x reference)
//
#include <hip/hip_runtime.h>

typedef unsigned short u16;
typedef __attribute__((ext_vector_type(8))) short bf16x8;
typedef __attribute__((ext_vector_type(4))) float f32x4;

__device__ inline u16 f2bf(float f) {
    union { float f; unsigned u; } v; v.f = f;
    unsigned r = v.u + 0x7fff + ((v.u >> 16) & 1);
    return (u16)(r >> 16);
}
__device__ inline float bflo(unsigned u) {
    union { unsigned u; float f; } v; v.u = u << 16; return v.f;
}
__device__ inline float bfhi(unsigned u) {
    union { unsigned u; float f; } v; v.u = u & 0xffff0000u; return v.f;
}
__device__ inline float bfs(u16 x) { return bflo((unsigned)x); }

// ---------------------------------------------------------------------------
// bucketed CSR build: bucket = 128 consecutive dst nodes.
// ---------------------------------------------------------------------------
__global__ void zero_int_k(int* __restrict__ p, int n) {
    int i = blockIdx.x * 256 + threadIdx.x;
    if (i < n) p[i] = 0;
}

__global__ void bucket_cnt_k(const int* __restrict__ dst, int* __restrict__ bcnt, int E) {
    int e = blockIdx.x * 256 + threadIdx.x;
    if (e < E) atomicAdd(&bcnt[dst[e] >> 7], 1);
}

// single-block exclusive scan of bcnt[nb] -> bptr[nb+1], bcur[nb]  (nb <= 1024)
__global__ void bscan_k(const int* __restrict__ bcnt, int* __restrict__ bptr,
                        int* __restrict__ bcur, int nb, int E) {
    __shared__ int lds[256];
    int t = threadIdx.x;
    int base = t * 4;
    int v[4];
    int s = 0;
#pragma unroll
    for (int i = 0; i < 4; ++i) {
        v[i] = s;
        int idx = base + i;
        s += (idx < nb) ? bcnt[idx] : 0;
    }
    int x = s;
    lds[t] = x;
    __syncthreads();
    for (int off = 1; off < 256; off <<= 1) {
        int y = (t >= off) ? lds[t - off] : 0;
        __syncthreads();
        x += y;
        lds[t] = x;
        __syncthreads();
    }
    int toff = x - s;
#pragma unroll
    for (int i = 0; i < 4; ++i) {
        int idx = base + i;
        if (idx < nb) {
            int e0 = toff + v[i];
            bptr[idx] = e0;
            bcur[idx] = e0;
        }
    }
    if (t == 255) bptr[nb] = E;
}

// scatter (src,dst) into bucket-contiguous tmp
__global__ void passB_k(const int* __restrict__ src, const int* __restrict__ dst,
                        int* __restrict__ bcur, int2* __restrict__ tmp, int E) {
    int e = blockIdx.x * 256 + threadIdx.x;
    if (e < E) {
        int s = src[e], d = dst[e];
        int p = atomicAdd(&bcur[d >> 7], 1);
        int2 sd; sd.x = s; sd.y = d;
        tmp[p] = sd;
    }
}

// per-bucket: LDS histogram -> rowptr/norm, LDS-cursor scatter -> esrc
__global__ __launch_bounds__(256) void passC_k(
    const int2* __restrict__ tmp, const int* __restrict__ bptr,
    int* __restrict__ rowptr, float* __restrict__ norm, int* __restrict__ esrc,
    int N, int E) {
    __shared__ int cnt[128];
    __shared__ int sc[128];
    __shared__ int cur[128];
    int b = blockIdx.x, t = threadIdx.x;
    int base = bptr[b], endp = bptr[b + 1];
    int node0 = b << 7;
    int nNodes = min(128, N - node0);

    if (t < 128) cnt[t] = 0;
    __syncthreads();
    for (int i = base + t; i < endp; i += 256)
        atomicAdd(&cnt[tmp[i].y & 127], 1);
    __syncthreads();
    if (t < 128) sc[t] = cnt[t];
    __syncthreads();
    for (int off = 1; off < 128; off <<= 1) {
        int y = 0;
        if (t < 128 && t >= off) y = sc[t - off];
        __syncthreads();
        if (t < 128) sc[t] += y;
        __syncthreads();
    }
    if (t < 128) {
        int ex = sc[t] - cnt[t];
        cur[t] = ex;
        if (t < nNodes) {
            rowptr[node0 + t] = base + ex;
            int d = cnt[t];
            norm[node0 + t] = (d > 0) ? rsqrtf((float)d) : 0.f;
        }
    }
    if (b == gridDim.x - 1 && t == 0) rowptr[N] = E;
    __syncthreads();
    for (int i = base + t; i < endp; i += 256) {
        int2 sd = tmp[i];
        int pos = atomicAdd(&cur[sd.y & 127], 1);
        esrc[base + pos] = sd.x;
    }
}

// ---------------------------------------------------------------------------
// prep: X -> bf16; W -> MFMA-fragment-packed bf16.
// Wp[((t*4+kk)*64+lane)*8+jj] = B[k][c], k = kk*32+(lane>>4)*8+jj, c = t*16+(lane&15)
// ---------------------------------------------------------------------------
__global__ void cvt_x_k(const float* __restrict__ X, u16* __restrict__ Xb, long n4) {
    long i = (long)blockIdx.x * 256 + threadIdx.x;
    if (i >= n4) return;
    float4 v = ((const float4*)X)[i];
    ushort4 o;
    o.x = f2bf(v.x); o.y = f2bf(v.y); o.z = f2bf(v.z); o.w = f2bf(v.w);
    ((ushort4*)Xb)[i] = o;
}

__global__ void pack_w1_k(const float* __restrict__ W1, u16* __restrict__ Wp) {
    int i = blockIdx.x * 256 + threadIdx.x;
    if (i >= 3 * 16384) return;
    int m = i >> 14, r = i & 16383;
    int jj = r & 7, lane = (r >> 3) & 63, kk = (r >> 9) & 3, t = r >> 11;
    int k = kk * 32 + (lane >> 4) * 8 + jj;
    int c = t * 16 + (lane & 15);
    Wp[i] = f2bf(W1[(size_t)m * 16384 + k * 128 + c]);
}

__global__ void pack_w2_k(const float* __restrict__ W2, u16* __restrict__ Wp) {
    int i = blockIdx.x * 256 + threadIdx.x;
    if (i >= 16384) return;
    int jj = i & 7, lane = (i >> 3) & 63, kk = (i >> 9) & 3, t = i >> 11;
    int k = kk * 32 + (lane >> 4) * 8 + jj;
    int c = t * 16 + (lane & 15);
    float v = 0.f;
    if (c < 120) {
        int hop = c / 40, j = c - hop * 40;
        v = W2[(size_t)(hop * 128 + k) * 40 + j];
    }
    Wp[i] = f2bf(v);
}

// ---------------------------------------------------------------------------
// MFMA GEMM: dot = A[n,128]b @ Wp.
// MODE 1: Cb = bf16(norm*dot)
// MODE 2: Cb = bf16(norm*(dot + norm*addp))      addp f32
// MODE 3: Cb = bf16(relu(dot + norm*addp + bias))
// MODE 0: Z0 f32[N][40] (c<40) | Z1 f32[N][40] (c<80) | Z2b bf16[N][40] (*norm)
// ---------------------------------------------------------------------------
template <int MODE>
__global__ __launch_bounds__(256, 2) void gemm_mfma_k(
    const u16* __restrict__ Ab, const u16* __restrict__ Wp,
    float* __restrict__ Cf, u16* __restrict__ Cb,
    float* __restrict__ Cf2, u16* __restrict__ Cb2,
    const float* __restrict__ addp, const float* __restrict__ bias,
    const float* __restrict__ norm, int n, int nStripes) {
    int lane = threadIdx.x & 63;
    int wave = threadIdx.x >> 6;
    int rit = lane & 15;
    int kgrp = lane >> 4;

    bf16x8 bfr[8][4];
    const bf16x8* wp = (const bf16x8*)Wp;
#pragma unroll
    for (int t = 0; t < 8; ++t)
#pragma unroll
        for (int kk = 0; kk < 4; ++kk)
            bfr[t][kk] = wp[(t * 4 + kk) * 64 + lane];

    for (int s = blockIdx.x; s < nStripes; s += gridDim.x) {
        int r0 = s * 64 + wave * 16;
        int ar = min(r0 + rit, n - 1);
        const bf16x8* arow = (const bf16x8*)(Ab + (size_t)ar * 128);
        bf16x8 afr[4];
#pragma unroll
        for (int kk = 0; kk < 4; ++kk) afr[kk] = arow[kk * 4 + kgrp];

        f32x4 acc[8];
#pragma unroll
        for (int t = 0; t < 8; ++t) acc[t] = (f32x4)(0.f);
#pragma unroll
        for (int kk = 0; kk < 4; ++kk)
#pragma unroll
            for (int t = 0; t < 8; ++t)
                acc[t] = __builtin_amdgcn_mfma_f32_16x16x32_bf16(
                    afr[kk], bfr[t][kk], acc[t], 0, 0, 0);

#pragma unroll
        for (int j = 0; j < 4; ++j) {
            int rs = r0 + kgrp * 4 + j;
            if (rs >= n) continue;
            float nr = norm[rs];
#pragma unroll
            for (int t = 0; t < 8; ++t) {
                int c = t * 16 + rit;
                float v = acc[t][j];
                if (MODE == 0) {
                    if (c < 40) Cf[(size_t)rs * 40 + c] = v;
                    else if (c < 80) Cf2[(size_t)rs * 40 + c - 40] = v;
                    else if (c < 120) Cb2[(size_t)rs * 40 + c - 80] = f2bf(v * nr);
                } else if (MODE == 1) {
                    Cb[(size_t)rs * 128 + c] = f2bf(v * nr);
                } else if (MODE == 2) {
                    float ap = addp[(size_t)rs * 128 + c];
                    Cb[(size_t)rs * 128 + c] = f2bf(nr * (v + nr * ap));
                } else {
                    float ap = addp[(size_t)rs * 128 + c];
                    float r = fmaxf(v + nr * ap + bias[c], 0.f);
                    Cb[(size_t)rs * 128 + c] = f2bf(r);
                }
            }
        }
    }
}

// out[n,:] = sum_{e in in(n)} in[src(e),:]; in bf16[N][128], out f32[N][128].
__global__ __launch_bounds__(256) void spmm128_bf_k(
    const u16* __restrict__ in, float* __restrict__ out,
    const int* __restrict__ rowptr, const int* __restrict__ esrc, int n) {
    int gw = (blockIdx.x * 256 + threadIdx.x) >> 6;
    if (gw >= n) return;
    int lane = threadIdx.x & 63;
    int sub = lane >> 4;
    int l16 = lane & 15;
    int beg = rowptr[gw], end = rowptr[gw + 1];
    float a[8];
#pragma unroll
    for (int j = 0; j < 8; ++j) a[j] = 0.f;

    int e = beg + sub;
    for (; e + 4 < end; e += 8) {
        int s0 = esrc[e], s1 = esrc[e + 4];
        uint4 v0 = *(const uint4*)(in + (size_t)s0 * 128 + l16 * 8);
        uint4 v1 = *(const uint4*)(in + (size_t)s1 * 128 + l16 * 8);
        a[0] += bflo(v0.x); a[1] += bfhi(v0.x);
        a[2] += bflo(v0.y); a[3] += bfhi(v0.y);
        a[4] += bflo(v0.z); a[5] += bfhi(v0.z);
        a[6] += bflo(v0.w); a[7] += bfhi(v0.w);
        a[0] += bflo(v1.x); a[1] += bfhi(v1.x);
        a[2] += bflo(v1.y); a[3] += bfhi(v1.y);
        a[4] += bflo(v1.z); a[5] += bfhi(v1.z);
        a[6] += bflo(v1.w); a[7] += bfhi(v1.w);
    }
    for (; e < end; e += 4) {
        int s = esrc[e];
        uint4 v = *(const uint4*)(in + (size_t)s * 128 + l16 * 8);
        a[0] += bflo(v.x); a[1] += bfhi(v.x);
        a[2] += bflo(v.y); a[3] += bfhi(v.y);
        a[4] += bflo(v.z); a[5] += bfhi(v.z);
        a[6] += bflo(v.w); a[7] += bfhi(v.w);
    }
#pragma unroll
    for (int j = 0; j < 8; ++j) {
        a[j] += __shfl_xor(a[j], 16);
        a[j] += __shfl_xor(a[j], 32);
    }
    if (sub == 0) {
        float4 o0; o0.x = a[0]; o0.y = a[1]; o0.z = a[2]; o0.w = a[3];
        float4 o1; o1.x = a[4]; o1.y = a[5]; o1.z = a[6]; o1.w = a[7];
        *(float4*)(out + (size_t)gw * 128 + l16 * 8) = o0;
        *(float4*)(out + (size_t)gw * 128 + l16 * 8 + 4) = o1;
    }
}

// u[n,j] = bf16( norm[n]*(Z1[n,j] + norm[n]*sum_e bf(Z2b[src(e),j])) ), j<40
__global__ __launch_bounds__(256) void spmm40_k(
    const u16* __restrict__ Z2b, const float* __restrict__ Z1, u16* __restrict__ u,
    const float* __restrict__ norm, const int* __restrict__ rowptr,
    const int* __restrict__ esrc, int n) {
    int gw = (blockIdx.x * 256 + threadIdx.x) >> 6;
    int lane = threadIdx.x & 63;
    if (gw >= n || lane >= 40) return;
    int beg = rowptr[gw], end = rowptr[gw + 1];
    float a = 0.f;
    int e = beg;
    for (; e + 3 < end; e += 4) {
        int s0 = esrc[e], s1 = esrc[e + 1], s2 = esrc[e + 2], s3 = esrc[e + 3];
        float v0 = bfs(Z2b[(size_t)s0 * 40 + lane]);
        float v1 = bfs(Z2b[(size_t)s1 * 40 + lane]);
        float v2 = bfs(Z2b[(size_t)s2 * 40 + lane]);
        float v3 = bfs(Z2b[(size_t)s3 * 40 + lane]);
        a += (v0 + v1) + (v2 + v3);
    }
    for (; e < end; ++e) a += bfs(Z2b[(size_t)esrc[e] * 40 + lane]);
    float nn = norm[gw];
    u[(size_t)gw * 40 + lane] = f2bf(nn * (Z1[(size_t)gw * 40 + lane] + nn * a));
}

// r = relu(Z0[n,:] + norm[n]*sum_e bf(u[src(e),:]) + b2); partial-sum for mean
__global__ __launch_bounds__(256) void spmm40_final_k(
    const u16* __restrict__ u, const float* __restrict__ Z0, const float* __restrict__ bias,
    float* __restrict__ partial, const float* __restrict__ norm,
    const int* __restrict__ rowptr, const int* __restrict__ esrc, int n, int nwaves) {
    __shared__ float lds[4][40];
    int wave = threadIdx.x >> 6;
    int lane = threadIdx.x & 63;
    int gw0 = blockIdx.x * 4 + wave;
    float accm = 0.f;
    float bb = (lane < 40) ? bias[lane] : 0.f;
    for (int node = gw0; node < n; node += nwaves) {
        if (lane < 40) {
            int beg = rowptr[node], end = rowptr[node + 1];
            float a = 0.f;
            int e = beg;
            for (; e + 3 < end; e += 4) {
                int s0 = esrc[e], s1 = esrc[e + 1], s2 = esrc[e + 2], s3 = esrc[e + 3];
                float v0 = bfs(u[(size_t)s0 * 40 + lane]);
                float v1 = bfs(u[(size_t)s1 * 40 + lane]);
                float v2 = bfs(u[(size_t)s2 * 40 + lane]);
                float v3 = bfs(u[(size_t)s3 * 40 + lane]);
                a += (v0 + v1) + (v2 + v3);
            }
            for (; e < end; ++e) a += bfs(u[(size_t)esrc[e] * 40 + lane]);
            float r = Z0[(size_t)node * 40 + lane] + norm[node] * a + bb;
            accm += fmaxf(r, 0.f);
        }
    }
    if (lane < 40) lds[wave][lane] = accm;
    __syncthreads();
    if (threadIdx.x < 40) {
        partial[blockIdx.x * 40 + threadIdx.x] =
            lds[0][threadIdx.x] + lds[1][threadIdx.x] + lds[2][threadIdx.x] + lds[3][threadIdx.x];
    }
}

__global__ __launch_bounds__(256) void reduce_mean_k(
    const float* __restrict__ partial, float* __restrict__ out, int nb, float invN) {
    __shared__ float lds[256];
    int c = blockIdx.x, t = threadIdx.x;
    float s = 0.f;
    for (int i = t; i < nb; i += 256) s += partial[(size_t)i * 40 + c];
    lds[t] = s;
    __syncthreads();
    for (int o = 128; o > 0; o >>= 1) {
        if (t < o) lds[t] += lds[t + o];
        __syncthreads();
    }
    if (t == 0) out[c] = lds[0] * invN;
}

extern "C" void kernel_launch(void* const* d_in, const int* in_sizes, int n_in,
                              void* d_out, int out_size, void* d_ws, size_t ws_size,
                              hipStream_t stream) {
    const float* X   = (const float*)d_in[0];
    const int*   src = (const int*)d_in[1];
    const int*   dst = (const int*)d_in[2];
    const float* W1  = (const float*)d_in[3];
    const float* b1  = (const float*)d_in[4];
    const float* W2  = (const float*)d_in[5];
    const float* b2  = (const float*)d_in[6];
    float* out = (float*)d_out;

    const int IN = 128;
    const int N = in_sizes[0] / IN;
    const int E = in_sizes[1];
    const int nb = (N + 127) >> 7;

    char* w = (char*)d_ws;
    size_t off = 0;
    auto alloc = [&](size_t bytes) -> char* {
        char* p = w + off;
        off = (off + bytes + 15) & ~(size_t)15;
        return p;
    };
    float* norm    = (float*)alloc((size_t)N * 4);
    int*   rowptr  = (int*)alloc((size_t)(N + 1) * 4);
    int*   bcnt    = (int*)alloc((size_t)(nb + 1) * 4);
    int*   bptr    = (int*)alloc((size_t)(nb + 1) * 4);
    int*   bcur    = (int*)alloc((size_t)(nb + 1) * 4);
    int*   esrc    = (int*)alloc((size_t)E * 4);
    u16*   Xb      = (u16*)alloc((size_t)N * 128 * 2);
    u16*   h1b     = (u16*)alloc((size_t)N * 128 * 2);
    u16*   g       = (u16*)alloc((size_t)N * 128 * 2);
    u16*   Wp1     = (u16*)alloc(3 * 16384 * 2);
    u16*   Wp2     = (u16*)alloc(16384 * 2);
    float* bufF    = (float*)alloc((size_t)N * 128 * 4);  // T; aliases tmp & Z0/Z1/Z2b
    u16*   ubuf    = (u16*)alloc((size_t)N * 40 * 2);
    float* partial = (float*)alloc(2048 * 40 * 4);

    int2*  tmp = (int2*)bufF;                       // preproc only (13 MB < 51 MB)
    float* Z0  = bufF;                              // [N][40] f32
    float* Z1  = bufF + (size_t)N * 40;             // [N][40] f32
    u16*   Z2b = (u16*)(bufF + (size_t)2 * N * 40); // [N][40] bf16

    // ---- bucketed CSR build ----
    zero_int_k<<<(nb + 255) / 256, 256, 0, stream>>>(bcnt, nb);
    bucket_cnt_k<<<(E + 255) / 256, 256, 0, stream>>>(dst, bcnt, E);
    bscan_k<<<1, 256, 0, stream>>>(bcnt, bptr, bcur, nb, E);
    passB_k<<<(E + 255) / 256, 256, 0, stream>>>(src, dst, bcur, tmp, E);
    passC_k<<<nb, 256, 0, stream>>>(tmp, bptr, rowptr, norm, esrc, N, E);

    // ---- bf16 prep ----
    long n4 = (long)N * 128 / 4;
    cvt_x_k<<<(int)((n4 + 255) / 256), 256, 0, stream>>>(X, Xb, n4);
    pack_w1_k<<<(3 * 16384 + 255) / 256, 256, 0, stream>>>(W1, Wp1);
    pack_w2_k<<<(16384 + 255) / 256, 256, 0, stream>>>(W2, Wp2);

    int nStripes = (N + 63) / 64;
    int gemm_grid = 512;
    int spmm_grid = (N + 3) / 4;

    // ---- layer 1: h1 = relu(X@W0 + A(X@W1 + A(X@W2)) + b1) ----
    gemm_mfma_k<1><<<gemm_grid, 256, 0, stream>>>(
        Xb, Wp1 + 2 * 16384, nullptr, g, nullptr, nullptr, nullptr, nullptr, norm, N, nStripes);
    spmm128_bf_k<<<spmm_grid, 256, 0, stream>>>(g, bufF, rowptr, esrc, N);
    gemm_mfma_k<2><<<gemm_grid, 256, 0, stream>>>(
        Xb, Wp1 + 1 * 16384, nullptr, g, nullptr, nullptr, bufF, nullptr, norm, N, nStripes);
    spmm128_bf_k<<<spmm_grid, 256, 0, stream>>>(g, bufF, rowptr, esrc, N);
    gemm_mfma_k<3><<<gemm_grid, 256, 0, stream>>>(
        Xb, Wp1, nullptr, h1b, nullptr, nullptr, bufF, b1, norm, N, nStripes);

    // ---- layer 2: out = mean(relu(Z0 + A(Z1 + A(Z2)) + b2)) ----
    gemm_mfma_k<0><<<gemm_grid, 256, 0, stream>>>(
        h1b, Wp2, Z0, nullptr, Z1, Z2b, nullptr, nullptr, norm, N, nStripes);
    spmm40_k<<<spmm_grid, 256, 0, stream>>>(Z2b, Z1, ubuf, norm, rowptr, esrc, N);
    spmm40_final_k<<<2048, 256, 0, stream>>>(ubuf, Z0, b2, partial, norm, rowptr, esrc, N, 8192);
    reduce_mean_k<<<40, 256, 0, stream>>>(partial, out, 2048, 1.f / (float)N);
}

// Round 7
// 444.626 us; speedup vs baseline: 2.5814x; 2.5814x over previous
//
#include <hip/hip_runtime.h>

typedef unsigned short u16;
typedef __attribute__((ext_vector_type(8))) short bf16x8;
typedef __attribute__((ext_vector_type(4))) float f32x4;

#define CSR_CHUNK 12288   // edges per block in CSR-build passes

__device__ inline u16 f2bf(float f) {
    union { float f; unsigned u; } v; v.f = f;
    unsigned r = v.u + 0x7fff + ((v.u >> 16) & 1);
    return (u16)(r >> 16);
}
__device__ inline float bflo(unsigned u) {
    union { unsigned u; float f; } v; v.u = u << 16; return v.f;
}
__device__ inline float bfhi(unsigned u) {
    union { unsigned u; float f; } v; v.u = u & 0xffff0000u; return v.f;
}
__device__ inline float bfs(u16 x) { return bflo((unsigned)x); }

// ---------------------------------------------------------------------------
// bucketed CSR build: bucket = 128 consecutive dst nodes (nb <= 1024).
// Hot-atomic contention avoided via block-local LDS histograms:
// global atomics are one-per-(block,bucket), ~131 per address.
// ---------------------------------------------------------------------------
__global__ void zero_int_k(int* __restrict__ p, int n) {
    int i = blockIdx.x * 256 + threadIdx.x;
    if (i < n) p[i] = 0;
}

__global__ __launch_bounds__(256) void bucket_cnt_k(
    const int* __restrict__ dst, int* __restrict__ bcnt, int E, int nbuck) {
    __shared__ int hist[1024];
    int e0 = blockIdx.x * CSR_CHUNK;
    int e1 = min(e0 + CSR_CHUNK, E);
    for (int i = threadIdx.x; i < nbuck; i += 256) hist[i] = 0;
    __syncthreads();
    for (int e = e0 + threadIdx.x; e < e1; e += 256)
        atomicAdd(&hist[dst[e] >> 7], 1);
    __syncthreads();
    for (int i = threadIdx.x; i < nbuck; i += 256) {
        int c = hist[i];
        if (c) atomicAdd(&bcnt[i], c);
    }
}

// single-block exclusive scan of bcnt[nb] -> bptr[nb+1], bcur[nb]
__global__ void bscan_k(const int* __restrict__ bcnt, int* __restrict__ bptr,
                        int* __restrict__ bcur, int nb, int E) {
    __shared__ int lds[256];
    int t = threadIdx.x;
    int base = t * 4;
    int v[4];
    int s = 0;
#pragma unroll
    for (int i = 0; i < 4; ++i) {
        v[i] = s;
        int idx = base + i;
        s += (idx < nb) ? bcnt[idx] : 0;
    }
    int x = s;
    lds[t] = x;
    __syncthreads();
    for (int off = 1; off < 256; off <<= 1) {
        int y = (t >= off) ? lds[t - off] : 0;
        __syncthreads();
        x += y;
        lds[t] = x;
        __syncthreads();
    }
    int toff = x - s;
#pragma unroll
    for (int i = 0; i < 4; ++i) {
        int idx = base + i;
        if (idx < nb) {
            int e0 = toff + v[i];
            bptr[idx] = e0;
            bcur[idx] = e0;
        }
    }
    if (t == 255) bptr[nb] = E;
}

// scatter (src,dst) into bucket-contiguous tmp; block-local LDS aggregation
__global__ __launch_bounds__(256) void passB_k(
    const int* __restrict__ src, const int* __restrict__ dst,
    int* __restrict__ bcur, int2* __restrict__ tmp, int E, int nbuck) {
    __shared__ int hist[1024];
    __shared__ int bbase[1024];
    int e0 = blockIdx.x * CSR_CHUNK;
    int e1 = min(e0 + CSR_CHUNK, E);
    for (int i = threadIdx.x; i < nbuck; i += 256) hist[i] = 0;
    __syncthreads();
    for (int e = e0 + threadIdx.x; e < e1; e += 256)
        atomicAdd(&hist[dst[e] >> 7], 1);
    __syncthreads();
    for (int i = threadIdx.x; i < nbuck; i += 256) {
        int c = hist[i];
        bbase[i] = c ? atomicAdd(&bcur[i], c) : 0;
        hist[i] = 0;
    }
    __syncthreads();
    for (int e = e0 + threadIdx.x; e < e1; e += 256) {
        int s = src[e], d = dst[e];
        int b = d >> 7;
        int r = atomicAdd(&hist[b], 1);
        int2 sd; sd.x = s; sd.y = d;
        tmp[bbase[b] + r] = sd;
    }
}

// per-bucket: LDS histogram -> rowptr/norm, LDS-cursor scatter -> esrc
__global__ __launch_bounds__(256) void passC_k(
    const int2* __restrict__ tmp, const int* __restrict__ bptr,
    int* __restrict__ rowptr, float* __restrict__ norm, int* __restrict__ esrc,
    int N, int E) {
    __shared__ int cnt[128];
    __shared__ int sc[128];
    __shared__ int cur[128];
    int b = blockIdx.x, t = threadIdx.x;
    int base = bptr[b], endp = bptr[b + 1];
    int node0 = b << 7;
    int nNodes = min(128, N - node0);

    if (t < 128) cnt[t] = 0;
    __syncthreads();
    for (int i = base + t; i < endp; i += 256)
        atomicAdd(&cnt[tmp[i].y & 127], 1);
    __syncthreads();
    if (t < 128) sc[t] = cnt[t];
    __syncthreads();
    for (int off = 1; off < 128; off <<= 1) {
        int y = 0;
        if (t < 128 && t >= off) y = sc[t - off];
        __syncthreads();
        if (t < 128) sc[t] += y;
        __syncthreads();
    }
    if (t < 128) {
        int ex = sc[t] - cnt[t];
        cur[t] = ex;
        if (t < nNodes) {
            rowptr[node0 + t] = base + ex;
            int d = cnt[t];
            norm[node0 + t] = (d > 0) ? rsqrtf((float)d) : 0.f;
        }
    }
    if (b == gridDim.x - 1 && t == 0) rowptr[N] = E;
    __syncthreads();
    for (int i = base + t; i < endp; i += 256) {
        int2 sd = tmp[i];
        int pos = atomicAdd(&cur[sd.y & 127], 1);
        esrc[base + pos] = sd.x;
    }
}

// ---------------------------------------------------------------------------
// prep: X -> bf16; W -> MFMA-fragment-packed bf16.
// Wp[((t*4+kk)*64+lane)*8+jj] = B[k][c], k = kk*32+(lane>>4)*8+jj, c = t*16+(lane&15)
// ---------------------------------------------------------------------------
__global__ void cvt_x_k(const float* __restrict__ X, u16* __restrict__ Xb, long n4) {
    long i = (long)blockIdx.x * 256 + threadIdx.x;
    if (i >= n4) return;
    float4 v = ((const float4*)X)[i];
    ushort4 o;
    o.x = f2bf(v.x); o.y = f2bf(v.y); o.z = f2bf(v.z); o.w = f2bf(v.w);
    ((ushort4*)Xb)[i] = o;
}

__global__ void pack_w1_k(const float* __restrict__ W1, u16* __restrict__ Wp) {
    int i = blockIdx.x * 256 + threadIdx.x;
    if (i >= 3 * 16384) return;
    int m = i >> 14, r = i & 16383;
    int jj = r & 7, lane = (r >> 3) & 63, kk = (r >> 9) & 3, t = r >> 11;
    int k = kk * 32 + (lane >> 4) * 8 + jj;
    int c = t * 16 + (lane & 15);
    Wp[i] = f2bf(W1[(size_t)m * 16384 + k * 128 + c]);
}

__global__ void pack_w2_k(const float* __restrict__ W2, u16* __restrict__ Wp) {
    int i = blockIdx.x * 256 + threadIdx.x;
    if (i >= 16384) return;
    int jj = i & 7, lane = (i >> 3) & 63, kk = (i >> 9) & 3, t = i >> 11;
    int k = kk * 32 + (lane >> 4) * 8 + jj;
    int c = t * 16 + (lane & 15);
    float v = 0.f;
    if (c < 120) {
        int hop = c / 40, j = c - hop * 40;
        v = W2[(size_t)(hop * 128 + k) * 40 + j];
    }
    Wp[i] = f2bf(v);
}

// ---------------------------------------------------------------------------
// MFMA GEMM: dot = A[n,128]b @ Wp.
// MODE 1: Cb = bf16(norm*dot)
// MODE 2: Cb = bf16(norm*(dot + norm*addp))      addp f32
// MODE 3: Cb = bf16(relu(dot + norm*addp + bias))
// MODE 0: Z0 f32[N][40] (c<40) | Z1 f32[N][40] (c<80) | Z2b bf16[N][40] (*norm)
// ---------------------------------------------------------------------------
template <int MODE>
__global__ __launch_bounds__(256, 2) void gemm_mfma_k(
    const u16* __restrict__ Ab, const u16* __restrict__ Wp,
    float* __restrict__ Cf, u16* __restrict__ Cb,
    float* __restrict__ Cf2, u16* __restrict__ Cb2,
    const float* __restrict__ addp, const float* __restrict__ bias,
    const float* __restrict__ norm, int n, int nStripes) {
    int lane = threadIdx.x & 63;
    int wave = threadIdx.x >> 6;
    int rit = lane & 15;
    int kgrp = lane >> 4;

    bf16x8 bfr[8][4];
    const bf16x8* wp = (const bf16x8*)Wp;
#pragma unroll
    for (int t = 0; t < 8; ++t)
#pragma unroll
        for (int kk = 0; kk < 4; ++kk)
            bfr[t][kk] = wp[(t * 4 + kk) * 64 + lane];

    for (int s = blockIdx.x; s < nStripes; s += gridDim.x) {
        int r0 = s * 64 + wave * 16;
        int ar = min(r0 + rit, n - 1);
        const bf16x8* arow = (const bf16x8*)(Ab + (size_t)ar * 128);
        bf16x8 afr[4];
#pragma unroll
        for (int kk = 0; kk < 4; ++kk) afr[kk] = arow[kk * 4 + kgrp];

        f32x4 acc[8];
#pragma unroll
        for (int t = 0; t < 8; ++t) acc[t] = (f32x4)(0.f);
#pragma unroll
        for (int kk = 0; kk < 4; ++kk)
#pragma unroll
            for (int t = 0; t < 8; ++t)
                acc[t] = __builtin_amdgcn_mfma_f32_16x16x32_bf16(
                    afr[kk], bfr[t][kk], acc[t], 0, 0, 0);

#pragma unroll
        for (int j = 0; j < 4; ++j) {
            int rs = r0 + kgrp * 4 + j;
            if (rs >= n) continue;
            float nr = norm[rs];
#pragma unroll
            for (int t = 0; t < 8; ++t) {
                int c = t * 16 + rit;
                float v = acc[t][j];
                if (MODE == 0) {
                    if (c < 40) Cf[(size_t)rs * 40 + c] = v;
                    else if (c < 80) Cf2[(size_t)rs * 40 + c - 40] = v;
                    else if (c < 120) Cb2[(size_t)rs * 40 + c - 80] = f2bf(v * nr);
                } else if (MODE == 1) {
                    Cb[(size_t)rs * 128 + c] = f2bf(v * nr);
                } else if (MODE == 2) {
                    float ap = addp[(size_t)rs * 128 + c];
                    Cb[(size_t)rs * 128 + c] = f2bf(nr * (v + nr * ap));
                } else {
                    float ap = addp[(size_t)rs * 128 + c];
                    float r = fmaxf(v + nr * ap + bias[c], 0.f);
                    Cb[(size_t)rs * 128 + c] = f2bf(r);
                }
            }
        }
    }
}

// out[n,:] = sum_{e in in(n)} in[src(e),:]; in bf16[N][128], out f32[N][128].
__global__ __launch_bounds__(256) void spmm128_bf_k(
    const u16* __restrict__ in, float* __restrict__ out,
    const int* __restrict__ rowptr, const int* __restrict__ esrc, int n) {
    int gw = (blockIdx.x * 256 + threadIdx.x) >> 6;
    if (gw >= n) return;
    int lane = threadIdx.x & 63;
    int sub = lane >> 4;
    int l16 = lane & 15;
    int beg = rowptr[gw], end = rowptr[gw + 1];
    float a[8];
#pragma unroll
    for (int j = 0; j < 8; ++j) a[j] = 0.f;

    int e = beg + sub;
    for (; e + 4 < end; e += 8) {
        int s0 = esrc[e], s1 = esrc[e + 4];
        uint4 v0 = *(const uint4*)(in + (size_t)s0 * 128 + l16 * 8);
        uint4 v1 = *(const uint4*)(in + (size_t)s1 * 128 + l16 * 8);
        a[0] += bflo(v0.x); a[1] += bfhi(v0.x);
        a[2] += bflo(v0.y); a[3] += bfhi(v0.y);
        a[4] += bflo(v0.z); a[5] += bfhi(v0.z);
        a[6] += bflo(v0.w); a[7] += bfhi(v0.w);
        a[0] += bflo(v1.x); a[1] += bfhi(v1.x);
        a[2] += bflo(v1.y); a[3] += bfhi(v1.y);
        a[4] += bflo(v1.z); a[5] += bfhi(v1.z);
        a[6] += bflo(v1.w); a[7] += bfhi(v1.w);
    }
    for (; e < end; e += 4) {
        int s = esrc[e];
        uint4 v = *(const uint4*)(in + (size_t)s * 128 + l16 * 8);
        a[0] += bflo(v.x); a[1] += bfhi(v.x);
        a[2] += bflo(v.y); a[3] += bfhi(v.y);
        a[4] += bflo(v.z); a[5] += bfhi(v.z);
        a[6] += bflo(v.w); a[7] += bfhi(v.w);
    }
#pragma unroll
    for (int j = 0; j < 8; ++j) {
        a[j] += __shfl_xor(a[j], 16);
        a[j] += __shfl_xor(a[j], 32);
    }
    if (sub == 0) {
        float4 o0; o0.x = a[0]; o0.y = a[1]; o0.z = a[2]; o0.w = a[3];
        float4 o1; o1.x = a[4]; o1.y = a[5]; o1.z = a[6]; o1.w = a[7];
        *(float4*)(out + (size_t)gw * 128 + l16 * 8) = o0;
        *(float4*)(out + (size_t)gw * 128 + l16 * 8 + 4) = o1;
    }
}

// u[n,j] = bf16( norm[n]*(Z1[n,j] + norm[n]*sum_e bf(Z2b[src(e),j])) ), j<40
__global__ __launch_bounds__(256) void spmm40_k(
    const u16* __restrict__ Z2b, const float* __restrict__ Z1, u16* __restrict__ u,
    const float* __restrict__ norm, const int* __restrict__ rowptr,
    const int* __restrict__ esrc, int n) {
    int gw = (blockIdx.x * 256 + threadIdx.x) >> 6;
    int lane = threadIdx.x & 63;
    if (gw >= n || lane >= 40) return;
    int beg = rowptr[gw], end = rowptr[gw + 1];
    float a = 0.f;
    int e = beg;
    for (; e + 3 < end; e += 4) {
        int s0 = esrc[e], s1 = esrc[e + 1], s2 = esrc[e + 2], s3 = esrc[e + 3];
        float v0 = bfs(Z2b[(size_t)s0 * 40 + lane]);
        float v1 = bfs(Z2b[(size_t)s1 * 40 + lane]);
        float v2 = bfs(Z2b[(size_t)s2 * 40 + lane]);
        float v3 = bfs(Z2b[(size_t)s3 * 40 + lane]);
        a += (v0 + v1) + (v2 + v3);
    }
    for (; e < end; ++e) a += bfs(Z2b[(size_t)esrc[e] * 40 + lane]);
    float nn = norm[gw];
    u[(size_t)gw * 40 + lane] = f2bf(nn * (Z1[(size_t)gw * 40 + lane] + nn * a));
}

// r = relu(Z0[n,:] + norm[n]*sum_e bf(u[src(e),:]) + b2); partial-sum for mean
__global__ __launch_bounds__(256) void spmm40_final_k(
    const u16* __restrict__ u, const float* __restrict__ Z0, const float* __restrict__ bias,
    float* __restrict__ partial, const float* __restrict__ norm,
    const int* __restrict__ rowptr, const int* __restrict__ esrc, int n, int nwaves) {
    __shared__ float lds[4][40];
    int wave = threadIdx.x >> 6;
    int lane = threadIdx.x & 63;
    int gw0 = blockIdx.x * 4 + wave;
    float accm = 0.f;
    float bb = (lane < 40) ? bias[lane] : 0.f;
    for (int node = gw0; node < n; node += nwaves) {
        if (lane < 40) {
            int beg = rowptr[node], end = rowptr[node + 1];
            float a = 0.f;
            int e = beg;
            for (; e + 3 < end; e += 4) {
                int s0 = esrc[e], s1 = esrc[e + 1], s2 = esrc[e + 2], s3 = esrc[e + 3];
                float v0 = bfs(u[(size_t)s0 * 40 + lane]);
                float v1 = bfs(u[(size_t)s1 * 40 + lane]);
                float v2 = bfs(u[(size_t)s2 * 40 + lane]);
                float v3 = bfs(u[(size_t)s3 * 40 + lane]);
                a += (v0 + v1) + (v2 + v3);
            }
            for (; e < end; ++e) a += bfs(u[(size_t)esrc[e] * 40 + lane]);
            float r = Z0[(size_t)node * 40 + lane] + norm[node] * a + bb;
            accm += fmaxf(r, 0.f);
        }
    }
    if (lane < 40) lds[wave][lane] = accm;
    __syncthreads();
    if (threadIdx.x < 40) {
        partial[blockIdx.x * 40 + threadIdx.x] =
            lds[0][threadIdx.x] + lds[1][threadIdx.x] + lds[2][threadIdx.x] + lds[3][threadIdx.x];
    }
}

__global__ __launch_bounds__(256) void reduce_mean_k(
    const float* __restrict__ partial, float* __restrict__ out, int nb, float invN) {
    __shared__ float lds[256];
    int c = blockIdx.x, t = threadIdx.x;
    float s = 0.f;
    for (int i = t; i < nb; i += 256) s += partial[(size_t)i * 40 + c];
    lds[t] = s;
    __syncthreads();
    for (int o = 128; o > 0; o >>= 1) {
        if (t < o) lds[t] += lds[t + o];
        __syncthreads();
    }
    if (t == 0) out[c] = lds[0] * invN;
}

extern "C" void kernel_launch(void* const* d_in, const int* in_sizes, int n_in,
                              void* d_out, int out_size, void* d_ws, size_t ws_size,
                              hipStream_t stream) {
    const float* X   = (const float*)d_in[0];
    const int*   src = (const int*)d_in[1];
    const int*   dst = (const int*)d_in[2];
    const float* W1  = (const float*)d_in[3];
    const float* b1  = (const float*)d_in[4];
    const float* W2  = (const float*)d_in[5];
    const float* b2  = (const float*)d_in[6];
    float* out = (float*)d_out;

    const int IN = 128;
    const int N = in_sizes[0] / IN;
    const int E = in_sizes[1];
    const int nb = (N + 127) >> 7;   // buckets of 128 nodes (<= 1024)

    char* w = (char*)d_ws;
    size_t off = 0;
    auto alloc = [&](size_t bytes) -> char* {
        char* p = w + off;
        off = (off + bytes + 15) & ~(size_t)15;
        return p;
    };
    float* norm    = (float*)alloc((size_t)N * 4);
    int*   rowptr  = (int*)alloc((size_t)(N + 1) * 4);
    int*   bcnt    = (int*)alloc((size_t)(nb + 1) * 4);
    int*   bptr    = (int*)alloc((size_t)(nb + 1) * 4);
    int*   bcur    = (int*)alloc((size_t)(nb + 1) * 4);
    int*   esrc    = (int*)alloc((size_t)E * 4);
    u16*   Xb      = (u16*)alloc((size_t)N * 128 * 2);
    u16*   h1b     = (u16*)alloc((size_t)N * 128 * 2);
    u16*   g       = (u16*)alloc((size_t)N * 128 * 2);
    u16*   Wp1     = (u16*)alloc(3 * 16384 * 2);
    u16*   Wp2     = (u16*)alloc(16384 * 2);
    float* bufF    = (float*)alloc((size_t)N * 128 * 4);  // T; aliases tmp & Z0/Z1/Z2b
    u16*   ubuf    = (u16*)alloc((size_t)N * 40 * 2);
    float* partial = (float*)alloc(2048 * 40 * 4);

    int2*  tmp = (int2*)bufF;                       // preproc only (13 MB < 51 MB)
    float* Z0  = bufF;                              // [N][40] f32
    float* Z1  = bufF + (size_t)N * 40;             // [N][40] f32
    u16*   Z2b = (u16*)(bufF + (size_t)2 * N * 40); // [N][40] bf16

    int csr_blocks = (E + CSR_CHUNK - 1) / CSR_CHUNK;

    // ---- bucketed CSR build (LDS-aggregated atomics) ----
    zero_int_k<<<(nb + 255) / 256, 256, 0, stream>>>(bcnt, nb);
    bucket_cnt_k<<<csr_blocks, 256, 0, stream>>>(dst, bcnt, E, nb);
    bscan_k<<<1, 256, 0, stream>>>(bcnt, bptr, bcur, nb, E);
    passB_k<<<csr_blocks, 256, 0, stream>>>(src, dst, bcur, tmp, E, nb);
    passC_k<<<nb, 256, 0, stream>>>(tmp, bptr, rowptr, norm, esrc, N, E);

    // ---- bf16 prep ----
    long n4 = (long)N * 128 / 4;
    cvt_x_k<<<(int)((n4 + 255) / 256), 256, 0, stream>>>(X, Xb, n4);
    pack_w1_k<<<(3 * 16384 + 255) / 256, 256, 0, stream>>>(W1, Wp1);
    pack_w2_k<<<(16384 + 255) / 256, 256, 0, stream>>>(W2, Wp2);

    int nStripes = (N + 63) / 64;
    int gemm_grid = 512;
    int spmm_grid = (N + 3) / 4;

    // ---- layer 1: h1 = relu(X@W0 + A(X@W1 + A(X@W2)) + b1) ----
    gemm_mfma_k<1><<<gemm_grid, 256, 0, stream>>>(
        Xb, Wp1 + 2 * 16384, nullptr, g, nullptr, nullptr, nullptr, nullptr, norm, N, nStripes);
    spmm128_bf_k<<<spmm_grid, 256, 0, stream>>>(g, bufF, rowptr, esrc, N);
    gemm_mfma_k<2><<<gemm_grid, 256, 0, stream>>>(
        Xb, Wp1 + 1 * 16384, nullptr, g, nullptr, nullptr, bufF, nullptr, norm, N, nStripes);
    spmm128_bf_k<<<spmm_grid, 256, 0, stream>>>(g, bufF, rowptr, esrc, N);
    gemm_mfma_k<3><<<gemm_grid, 256, 0, stream>>>(
        Xb, Wp1, nullptr, h1b, nullptr, nullptr, bufF, b1, norm, N, nStripes);

    // ---- layer 2: out = mean(relu(Z0 + A(Z1 + A(Z2)) + b2)) ----
    gemm_mfma_k<0><<<gemm_grid, 256, 0, stream>>>(
        h1b, Wp2, Z0, nullptr, Z1, Z2b, nullptr, nullptr, norm, N, nStripes);
    spmm40_k<<<spmm_grid, 256, 0, stream>>>(Z2b, Z1, ubuf, norm, rowptr, esrc, N);
    spmm40_final_k<<<2048, 256, 0, stream>>>(ubuf, Z0, b2, partial, norm, rowptr, esrc, N, 8192);
    reduce_mean_k<<<40, 256, 0, stream>>>(partial, out, 2048, 1.f / (float)N);
}